// Round 5
// baseline (524.878 us; speedup 1.0000x reference)
//
#include <hip/hip_runtime.h>
#include <hip/hip_bf16.h>
#include <math.h>

// ---------------------------------------------------------------------------
// BitNet-b1.58 MLP: x -> bitlinear(W1,b1) -> gelu(erf) -> bitlinear(W2,b2)
// Exact-integer formulation: int8 x int8 -> int32 MFMA, dequant in epilogue.
// GEMM r5: 256x256 tile, BK=128, 8 waves, dbuf LDS, 32x32x32 i8 MFMA,
// 4 lockstep phases/tile with frag-register double-buffer (reads issued one
// sub-phase ahead), counted vmcnt(4), XOR swizzle, setprio, XCD swizzle.
// ---------------------------------------------------------------------------

typedef int int32x4 __attribute__((ext_vector_type(4)));
typedef int int32x16 __attribute__((ext_vector_type(16)));

typedef const void __attribute__((address_space(1))) gv_t;
typedef void __attribute__((address_space(3))) lv_t;

__device__ __forceinline__ void gload_lds16(const signed char* g,
                                            signed char* l) {
  __builtin_amdgcn_global_load_lds((gv_t*)g, (lv_t*)l, 16, 0, 0);
}

__device__ __forceinline__ float gelu_erf(float v) {
  return 0.5f * v * (1.0f + erff(v * 0.70710678118654752440f));
}

__device__ __forceinline__ unsigned short bf16_rne(float v) {
  unsigned u = __float_as_uint(v);
  u += 0x7fffu + ((u >> 16) & 1u);
  return (unsigned short)(u >> 16);
}

__device__ __forceinline__ void store4(float* p, const float o[4]) {
  float4 t; t.x = o[0]; t.y = o[1]; t.z = o[2]; t.w = o[3];
  *(float4*)p = t;
}
__device__ __forceinline__ void store4(__hip_bfloat16* p, const float o[4]) {
  ushort4 t;
  t.x = bf16_rne(o[0]); t.y = bf16_rne(o[1]);
  t.z = bf16_rne(o[2]); t.w = bf16_rne(o[3]);
  *(ushort4*)p = t;
}

__device__ __forceinline__ void load4v(const float* p, float v[4]) {
  const float4 t = *(const float4*)p;
  v[0] = t.x; v[1] = t.y; v[2] = t.z; v[3] = t.w;
}
__device__ __forceinline__ void load4v(const __hip_bfloat16* p, float v[4]) {
  const ushort4 t = *(const ushort4*)p;
  v[0] = __uint_as_float((unsigned)t.x << 16);
  v[1] = __uint_as_float((unsigned)t.y << 16);
  v[2] = __uint_as_float((unsigned)t.z << 16);
  v[3] = __uint_as_float((unsigned)t.w << 16);
}

// --------------------------- w_scale reduction ------------------------------
__global__ __launch_bounds__(256) void absmean_partial(
    const float* __restrict__ W, double* __restrict__ part) {
  const int tid = threadIdx.x;
  const long base = (long)blockIdx.x * 8192;
  double s = 0.0;
#pragma unroll
  for (int c = 0; c < 8; ++c) {
    const float4 v = *(const float4*)&W[base + c * 1024 + tid * 4];
    s += (double)fabsf(v.x) + (double)fabsf(v.y) +
         (double)fabsf(v.z) + (double)fabsf(v.w);
  }
  __shared__ double sm[256];
  sm[tid] = s; __syncthreads();
  for (int off = 128; off; off >>= 1) {
    if (tid < off) sm[tid] += sm[tid + off];
    __syncthreads();
  }
  if (tid == 0) part[blockIdx.x] = sm[0];
}

__global__ __launch_bounds__(256) void absmean_final(
    const double* __restrict__ part, double* __restrict__ out, double n) {
  const int tid = threadIdx.x;
  __shared__ double sm[256];
  sm[tid] = part[tid] + part[tid + 256];
  __syncthreads();
  for (int off = 128; off; off >>= 1) {
    if (tid < off) sm[tid] += sm[tid + off];
    __syncthreads();
  }
  if (tid == 0) out[0] = fmax(sm[0] / n, 1e-5);
}

// --------------------------- weight ternarization ---------------------------
__global__ __launch_bounds__(256) void quant_w(
    const float* __restrict__ W, const double* __restrict__ wsP,
    signed char* __restrict__ Wq) {
  const double ws = *wsP;
  const long i = ((long)blockIdx.x * 256 + threadIdx.x) * 4;
  const float4 v = *(const float4*)&W[i];
  const float vv[4] = {v.x, v.y, v.z, v.w};
  int pack = 0;
#pragma unroll
  for (int q = 0; q < 4; ++q) {
    double r = rint((double)vv[q] / ws);  // RNE, matches jnp.round
    r = fmin(fmax(r, -1.0), 1.0);
    pack |= (((int)r) & 0xff) << (8 * q);
  }
  *(int*)&Wq[i] = pack;
}

// --------------------------- per-token activation quant ---------------------
template <int L, bool GELU, typename GT>
__global__ __launch_bounds__(256) void quant_rows(
    const GT* __restrict__ X, signed char* __restrict__ Xq,
    float* __restrict__ dsc) {
  constexpr int CH = L / 1024;
  const long row = blockIdx.x;
  const int tid = threadIdx.x;
  const GT* xr = X + row * (long)L;
  float v[CH][4];
  float m = 0.f;
#pragma unroll
  for (int c = 0; c < CH; ++c) {
    load4v(xr + c * 1024 + tid * 4, v[c]);
#pragma unroll
    for (int q = 0; q < 4; ++q) {
      if (GELU) v[c][q] = gelu_erf(v[c][q]);
      m = fmaxf(m, fabsf(v[c][q]));
    }
  }
#pragma unroll
  for (int off = 32; off; off >>= 1) m = fmaxf(m, __shfl_down(m, off, 64));
  __shared__ float wmx[4];
  if ((tid & 63) == 0) wmx[tid >> 6] = m;
  __syncthreads();
  float ms = fmaxf(fmaxf(wmx[0], wmx[1]), fmaxf(wmx[2], wmx[3]));
  ms = fmaxf(ms, 1e-5f);
  const double inv = 127.0 / (double)ms;
#pragma unroll
  for (int c = 0; c < CH; ++c) {
    int pack = 0;
#pragma unroll
    for (int q = 0; q < 4; ++q) {
      double r = rint((double)v[c][q] * inv);
      r = fmin(fmax(r, -128.0), 127.0);
      pack |= (((int)r) & 0xff) << (8 * q);
    }
    *(int*)&Xq[row * (long)L + c * 1024 + tid * 4] = pack;
  }
  if (tid == 0) dsc[row] = (float)((double)ms / 127.0);
}

// --------------------------- int8 GEMM, 32x32 phase-ahead -------------------
// C[M][N] = A[M][K] * Bm[N][K]^T. LDS: A dbuf [0,64K), B dbuf [64K,128K).
// Tile rows are 128 B; swizzle: col7 ^= (row&7)<<4 (involution, both sides).
// Wave tile 128x64 = 4x2 grid of 32x32. Swapped operands mfma(bf, af):
// lane&31 = M-row, regs = N (n = (r&3) + 8*(r>>2) + 4*(lane>>5)).
template <typename GT>
__global__ __launch_bounds__(512, 2) void gemm_i8_32(
    const signed char* __restrict__ A, const signed char* __restrict__ Bm,
    const float* __restrict__ dA, const double* __restrict__ wsB,
    const float* __restrict__ bias, GT* __restrict__ C,
    int K, int Ncol, int nx) {
  __shared__ signed char LDS[131072];
  const int tid = threadIdx.x;
  const int lane = tid & 63;
  const int wave = tid >> 6;
  const int wm = wave >> 2;  // 0..1
  const int wn = wave & 3;   // 0..3

  const int cpx = gridDim.x >> 3;
  const int wg = ((int)blockIdx.x & 7) * cpx + ((int)blockIdx.x >> 3);
  const long rowBase = (long)(wg / nx) * 256;
  const long colBase = (long)(wg % nx) * 256;
  const int NT = K >> 7;  // BK = 128

  // ---- staging: 8 x 16B per thread per K-tile (4 per matrix) ----
  const int dd = tid << 4;                          // [0,8192)
  const int srow = dd >> 7;                         // 0..63
  const int scol = (dd & 127) ^ ((srow & 7) << 4);  // pre-swizzled src col
  const long k64 = 64L * K;
  const signed char* sA0 = A + (rowBase + srow) * (long)K + scol;
  const signed char* sB0 = Bm + (colBase + srow) * (long)K + scol;

  auto STAGE_A2 = [&](int t, int h) {
    const signed char* p = sA0 + ((long)t << 7) + (2 * h) * k64;
    signed char* l = &LDS[((t & 1) << 15) + dd + h * 16384];
    gload_lds16(p, l);
    gload_lds16(p + k64, l + 8192);
  };
  auto STAGE_B4 = [&](int t) {
    const signed char* p = sB0 + ((long)t << 7);
    signed char* l = &LDS[65536 + ((t & 1) << 15) + dd];
#pragma unroll
    for (int i = 0; i < 4; ++i) gload_lds16(p + i * k64, l + i * 8192);
  };

  // ---- fragment addressing (32x32x32: lane&31 = row, (lane>>5)*16 = k) ----
  const int ml = lane & 31;
  const int h16 = (lane >> 5) << 4;
  const int xm = (lane & 7) << 4;
  int rA[4], rB[2], colX[4];
#pragma unroll
  for (int tm = 0; tm < 4; ++tm) rA[tm] = (wm * 128 + tm * 32 + ml) * 128;
#pragma unroll
  for (int tn = 0; tn < 2; ++tn) rB[tn] = (wn * 64 + tn * 32 + ml) * 128;
#pragma unroll
  for (int s = 0; s < 4; ++s) colX[s] = ((s << 5) + h16) ^ xm;

  int32x16 acc[4][2] = {};
  int32x4 afA[4], bfA[2], afB[4], bfB[2];  // two fragment sets (ping-pong)

  // ---- prologue: B(0), A(0), B(1) staged ----
  STAGE_B4(0);
  STAGE_A2(0, 0); STAGE_A2(0, 1);
  STAGE_B4(1);

  for (int t = 0; t < NT; ++t) {
    if (t + 1 < NT) asm volatile("s_waitcnt vmcnt(4)" ::: "memory");
    else            asm volatile("s_waitcnt vmcnt(0)" ::: "memory");
    __builtin_amdgcn_s_barrier();

    const signed char* At = &LDS[(t & 1) << 15];
    const signed char* Bt = &LDS[65536 + ((t & 1) << 15)];

    auto LDF = [&](int32x4 af[4], int32x4 bf[2], int s) {
#pragma unroll
      for (int tn = 0; tn < 2; ++tn)
        bf[tn] = *(const int32x4*)(Bt + rB[tn] + colX[s]);
#pragma unroll
      for (int tm = 0; tm < 4; ++tm)
        af[tm] = *(const int32x4*)(At + rA[tm] + colX[s]);
    };
    auto MFMA8 = [&](int32x4 af[4], int32x4 bf[2]) {
      __builtin_amdgcn_s_setprio(1);
#pragma unroll
      for (int tm = 0; tm < 4; ++tm)
#pragma unroll
        for (int tn = 0; tn < 2; ++tn)
          acc[tm][tn] = __builtin_amdgcn_mfma_i32_32x32x32_i8(
              bf[tn], af[tm], acc[tm][tn], 0, 0, 0);
      __builtin_amdgcn_s_setprio(0);
    };

    // phase 0: load frags for s=0 AND s=1; stage A(t+1) half 0
    LDF(afA, bfA, 0);
    LDF(afB, bfB, 1);
    if (t + 1 < NT) STAGE_A2(t + 1, 0);
    __builtin_amdgcn_s_barrier();
    MFMA8(afA, bfA);

    // phase 1: prefetch s=2 frags; stage A(t+1) half 1; compute s=1
    LDF(afA, bfA, 2);
    if (t + 1 < NT) STAGE_A2(t + 1, 1);
    __builtin_amdgcn_s_barrier();
    MFMA8(afB, bfB);

    // phase 2: prefetch s=3 frags; compute s=2
    LDF(afB, bfB, 3);
    __builtin_amdgcn_s_barrier();
    MFMA8(afA, bfA);

    // phase 3: all B reads retired in all waves, then stage B(t+2); compute s=3
    asm volatile("s_waitcnt lgkmcnt(0)" ::: "memory");
    __builtin_amdgcn_s_barrier();
    if (t + 2 < NT) STAGE_B4(t + 2);
    MFMA8(afB, bfB);
  }

  // ---- epilogue: lane&31 = M-row; n = (r&3) + 8*(r>>2) + 4*(lane>>5) ----
  const double wsd = *wsB;
  const int h5 = (lane >> 5) << 2;
  float sc[4];
#pragma unroll
  for (int tm = 0; tm < 4; ++tm)
    sc[tm] = (float)((double)dA[rowBase + wm * 128 + tm * 32 + ml] * wsd);
  float4 bv[2][4];
#pragma unroll
  for (int tn = 0; tn < 2; ++tn)
#pragma unroll
    for (int rq = 0; rq < 4; ++rq)
      bv[tn][rq] =
          *(const float4*)&bias[colBase + wn * 64 + tn * 32 + h5 + rq * 8];
#pragma unroll
  for (int tm = 0; tm < 4; ++tm) {
    const long row = rowBase + wm * 128 + tm * 32 + ml;
    GT* crow = C + row * (long)Ncol + colBase + wn * 64 + h5;
#pragma unroll
    for (int tn = 0; tn < 2; ++tn) {
#pragma unroll
      for (int rq = 0; rq < 4; ++rq) {
        float o[4];
#pragma unroll
        for (int j = 0; j < 4; ++j) {
          const float bj = (j == 0) ? bv[tn][rq].x : (j == 1) ? bv[tn][rq].y
                           : (j == 2) ? bv[tn][rq].z : bv[tn][rq].w;
          o[j] = (float)acc[tm][tn][rq * 4 + j] * sc[tm] + bj;
        }
        store4(&crow[tn * 32 + rq * 8], o);
      }
    }
  }
}

// ---------------------------------------------------------------------------
extern "C" void kernel_launch(void* const* d_in, const int* in_sizes, int n_in,
                              void* d_out, int out_size, void* d_ws,
                              size_t ws_size, hipStream_t stream) {
  const float* x  = (const float*)d_in[0];
  const float* W1 = (const float*)d_in[1];
  const float* b1 = (const float*)d_in[2];
  const float* W2 = (const float*)d_in[3];
  const float* b2 = (const float*)d_in[4];
  const int D = in_sizes[4];             // 1024
  const int H = in_sizes[2];             // 4096
  const long M = (long)in_sizes[0] / D;  // 32768
  float* out = (float*)d_out;

  if (D != 1024 || H != 4096 || (M % 256) != 0) return;  // shape contract

  char* wsp = (char*)d_ws;
  size_t off = 0;
  auto alloc = [&](size_t bytes) {
    void* p = wsp + off;
    off = (off + bytes + 255) & ~(size_t)255;
    return p;
  };
  signed char* wq1 = (signed char*)alloc((size_t)H * D);
  signed char* wq2 = (signed char*)alloc((size_t)D * H);
  signed char* xq  = (signed char*)alloc((size_t)M * D);
  signed char* gq  = (signed char*)alloc((size_t)M * H);
  float* dx = (float*)alloc((size_t)M * 4);
  float* dg = (float*)alloc((size_t)M * 4);
  double* part = (double*)alloc(512 * 8);
  double* ws1 = (double*)alloc(8);
  double* ws2 = (double*)alloc(8);
  __hip_bfloat16* h = (__hip_bfloat16*)alloc((size_t)M * H * 2);
  if (off > ws_size) return;  // cannot run

  const long nW = (long)H * D;
  absmean_partial<<<nW / 8192, 256, 0, stream>>>(W1, part);
  absmean_final<<<1, 256, 0, stream>>>(part, ws1, (double)nW);
  absmean_partial<<<nW / 8192, 256, 0, stream>>>(W2, part);
  absmean_final<<<1, 256, 0, stream>>>(part, ws2, (double)nW);
  quant_w<<<nW / 1024, 256, 0, stream>>>(W1, ws1, wq1);
  quant_w<<<nW / 1024, 256, 0, stream>>>(W2, ws2, wq2);
  quant_rows<1024, false, float><<<M, 256, 0, stream>>>(x, xq, dx);

  const int g1 = (H / 256) * (int)(M / 256);  // 2048
  const int g2 = (D / 256) * (int)(M / 256);  // 512
  gemm_i8_32<__hip_bfloat16><<<g1, 512, 0, stream>>>(
      xq, wq1, dx, ws1, b1, h, D, H, H / 256);
  quant_rows<4096, true, __hip_bfloat16><<<M, 256, 0, stream>>>(h, gq, dg);
  gemm_i8_32<float><<<g2, 512, 0, stream>>>(
      gq, wq2, dg, ws2, b2, out, H, D, D / 256);
}

// Round 6
// 466.355 us; speedup vs baseline: 1.1255x; 1.1255x over previous
//
#include <hip/hip_runtime.h>
#include <hip/hip_bf16.h>
#include <math.h>

// ---------------------------------------------------------------------------
// BitNet-b1.58 MLP: x -> bitlinear(W1,b1) -> gelu(erf) -> bitlinear(W2,b2)
// Exact-integer formulation: int8 x int8 -> int32 MFMA, dequant in epilogue.
// GEMM r6: faithful m201 8-phase port. 256x256 tile, BK=128 i8 (128B rows),
// 8 waves, dbuf LDS 128KB, 2 K-tiles per iteration, stages at ph1/2 (->buf1)
// and ph5/6 (->buf0), vmcnt(0) checkpoints at ph4/ph8 only (awaited loads
// are >=2 phases old), 2 barriers/phase, setprio, XOR swizzle, XCD swizzle.
// ---------------------------------------------------------------------------

typedef int int32x4 __attribute__((ext_vector_type(4)));

typedef const void __attribute__((address_space(1))) gv_t;
typedef void __attribute__((address_space(3))) lv_t;

__device__ __forceinline__ void gload_lds16(const signed char* g,
                                            signed char* l) {
  __builtin_amdgcn_global_load_lds((gv_t*)g, (lv_t*)l, 16, 0, 0);
}

__device__ __forceinline__ float gelu_erf(float v) {
  return 0.5f * v * (1.0f + erff(v * 0.70710678118654752440f));
}

__device__ __forceinline__ void store_gt(float* p, float v) { *p = v; }
__device__ __forceinline__ void store_gt(__hip_bfloat16* p, float v) {
  unsigned u = __float_as_uint(v);
  u += 0x7fffu + ((u >> 16) & 1u);  // RNE to bf16
  *(unsigned short*)p = (unsigned short)(u >> 16);
}

__device__ __forceinline__ void load4v(const float* p, float v[4]) {
  const float4 t = *(const float4*)p;
  v[0] = t.x; v[1] = t.y; v[2] = t.z; v[3] = t.w;
}
__device__ __forceinline__ void load4v(const __hip_bfloat16* p, float v[4]) {
  const ushort4 t = *(const ushort4*)p;
  v[0] = __uint_as_float((unsigned)t.x << 16);
  v[1] = __uint_as_float((unsigned)t.y << 16);
  v[2] = __uint_as_float((unsigned)t.z << 16);
  v[3] = __uint_as_float((unsigned)t.w << 16);
}

// --------------------------- w_scale reduction ------------------------------
__global__ __launch_bounds__(256) void absmean_partial(
    const float* __restrict__ W, double* __restrict__ part) {
  const int tid = threadIdx.x;
  const long base = (long)blockIdx.x * 8192;
  double s = 0.0;
#pragma unroll
  for (int c = 0; c < 8; ++c) {
    const float4 v = *(const float4*)&W[base + c * 1024 + tid * 4];
    s += (double)fabsf(v.x) + (double)fabsf(v.y) +
         (double)fabsf(v.z) + (double)fabsf(v.w);
  }
  __shared__ double sm[256];
  sm[tid] = s; __syncthreads();
  for (int off = 128; off; off >>= 1) {
    if (tid < off) sm[tid] += sm[tid + off];
    __syncthreads();
  }
  if (tid == 0) part[blockIdx.x] = sm[0];
}

__global__ __launch_bounds__(256) void absmean_final(
    const double* __restrict__ part, double* __restrict__ out, double n) {
  const int tid = threadIdx.x;
  __shared__ double sm[256];
  sm[tid] = part[tid] + part[tid + 256];
  __syncthreads();
  for (int off = 128; off; off >>= 1) {
    if (tid < off) sm[tid] += sm[tid + off];
    __syncthreads();
  }
  if (tid == 0) out[0] = fmax(sm[0] / n, 1e-5);
}

// --------------------------- weight ternarization ---------------------------
__global__ __launch_bounds__(256) void quant_w(
    const float* __restrict__ W, const double* __restrict__ wsP,
    signed char* __restrict__ Wq) {
  const double ws = *wsP;
  const long i = ((long)blockIdx.x * 256 + threadIdx.x) * 4;
  const float4 v = *(const float4*)&W[i];
  const float vv[4] = {v.x, v.y, v.z, v.w};
  int pack = 0;
#pragma unroll
  for (int q = 0; q < 4; ++q) {
    double r = rint((double)vv[q] / ws);  // RNE, matches jnp.round
    r = fmin(fmax(r, -1.0), 1.0);
    pack |= (((int)r) & 0xff) << (8 * q);
  }
  *(int*)&Wq[i] = pack;
}

// --------------------------- per-token activation quant ---------------------
template <int L, bool GELU, typename GT>
__global__ __launch_bounds__(256) void quant_rows(
    const GT* __restrict__ X, signed char* __restrict__ Xq,
    float* __restrict__ dsc) {
  constexpr int CH = L / 1024;
  const long row = blockIdx.x;
  const int tid = threadIdx.x;
  const GT* xr = X + row * (long)L;
  float v[CH][4];
  float m = 0.f;
#pragma unroll
  for (int c = 0; c < CH; ++c) {
    load4v(xr + c * 1024 + tid * 4, v[c]);
#pragma unroll
    for (int q = 0; q < 4; ++q) {
      if (GELU) v[c][q] = gelu_erf(v[c][q]);
      m = fmaxf(m, fabsf(v[c][q]));
    }
  }
#pragma unroll
  for (int off = 32; off; off >>= 1) m = fmaxf(m, __shfl_down(m, off, 64));
  __shared__ float wmx[4];
  if ((tid & 63) == 0) wmx[tid >> 6] = m;
  __syncthreads();
  float ms = fmaxf(fmaxf(wmx[0], wmx[1]), fmaxf(wmx[2], wmx[3]));
  ms = fmaxf(ms, 1e-5f);
  const double inv = 127.0 / (double)ms;
#pragma unroll
  for (int c = 0; c < CH; ++c) {
    int pack = 0;
#pragma unroll
    for (int q = 0; q < 4; ++q) {
      double r = rint((double)v[c][q] * inv);
      r = fmin(fmax(r, -128.0), 127.0);
      pack |= (((int)r) & 0xff) << (8 * q);
    }
    *(int*)&Xq[row * (long)L + c * 1024 + tid * 4] = pack;
  }
  if (tid == 0) dsc[row] = (float)((double)ms / 127.0);
}

// --------------------------- int8 GEMM, m201-faithful -----------------------
// C[M][N] = A[M][K] * Bm[N][K]^T. LDS: A dbuf [0,64K), B dbuf [64K,128K).
// Tile rows are 128 B; swizzle: col ^= (row&7)<<4 (involution, both sides).
// Iteration covers K-tiles (2it) [buf0] and (2it+1) [buf1], 8 phases.
// Stage plan: ph1/ph2 stage tile(2it+1)->buf1 (it>0); ph5/ph6 stage
// tile(2it+2)->buf0 (it<NI-1). Checkpoints vmcnt(0) at ph4/ph8 only.
template <typename GT>
__global__ __launch_bounds__(512, 2) void gemm_i8_m201(
    const signed char* __restrict__ A, const signed char* __restrict__ Bm,
    const float* __restrict__ dA, const double* __restrict__ wsB,
    const float* __restrict__ bias, GT* __restrict__ C,
    int K, int Ncol, int nx) {
  __shared__ signed char LDS[131072];
  const int tid = threadIdx.x;
  const int lane = tid & 63;
  const int wave = tid >> 6;
  const int wm = wave >> 2;  // 0..1
  const int wn = wave & 3;   // 0..3

  const int cpx = gridDim.x >> 3;
  const int wg = ((int)blockIdx.x & 7) * cpx + ((int)blockIdx.x >> 3);
  const long rowBase = (long)(wg / nx) * 256;
  const long colBase = (long)(wg % nx) * 256;
  const int NT = K >> 7;   // BK = 128
  const int NI = NT >> 1;  // 2 K-tiles per iteration

  // ---- staging: 4 x 16B per thread per matrix per K-tile ----
  const int dd = tid << 4;                          // [0,8192)
  const int srow = dd >> 7;                         // 0..63
  const int scol = (dd & 127) ^ ((srow & 7) << 4);  // pre-swizzled src col
  const long k64 = 64L * K;
  const signed char* sA0 = A + (rowBase + srow) * (long)K + scol;
  const signed char* sB0 = Bm + (colBase + srow) * (long)K + scol;

  auto STAGE_A = [&](int t) {
    const signed char* p = sA0 + ((long)t << 7);
    signed char* l = &LDS[((t & 1) << 15) + dd];
#pragma unroll
    for (int i = 0; i < 4; ++i) gload_lds16(p + i * k64, l + i * 8192);
  };
  auto STAGE_B = [&](int t) {
    const signed char* p = sB0 + ((long)t << 7);
    signed char* l = &LDS[65536 + ((t & 1) << 15) + dd];
#pragma unroll
    for (int i = 0; i < 4; ++i) gload_lds16(p + i * k64, l + i * 8192);
  };

  // ---- ds_read fragment addressing ----
  const int rl = lane & 15;
  const int col0 = (((lane >> 4) << 4)) ^ ((rl & 7) << 4);  // swizzled col kc0
  const int aRow = wm * 16384 + rl * 128;  // within A tile
  const int bRow = wn * 8192 + rl * 128;   // within B tile

  int32x4 acc[8][4] = {};
  int32x4 af[4], bf[4];

  auto LDA = [&](const signed char* At, int mih, int kc6) {
#pragma unroll
    for (int i = 0; i < 4; ++i)
      af[i] = *(const int32x4*)(At + aRow + (mih * 4 + i) * 2048 +
                                (col0 ^ kc6));
  };
  auto LDB = [&](const signed char* Bt, int kc6) {
#pragma unroll
    for (int nj = 0; nj < 4; ++nj)
      bf[nj] = *(const int32x4*)(Bt + bRow + nj * 2048 + (col0 ^ kc6));
  };
  auto MFMA16 = [&](int mih) {
    __builtin_amdgcn_s_setprio(1);
#pragma unroll
    for (int i = 0; i < 4; ++i)
#pragma unroll
      for (int nj = 0; nj < 4; ++nj)
        acc[mih * 4 + i][nj] = __builtin_amdgcn_mfma_i32_16x16x64_i8(
            af[i], bf[nj], acc[mih * 4 + i][nj], 0, 0, 0);
    __builtin_amdgcn_s_setprio(0);
  };

  // ---- prologue: stage tiles 0 (buf0) and 1 (buf1) ----
  STAGE_A(0); STAGE_B(0);
  STAGE_A(1); STAGE_B(1);
  asm volatile("s_waitcnt vmcnt(8)" ::: "memory");  // tile 0 complete
  __builtin_amdgcn_s_barrier();

  for (int it = 0; it < NI; ++it) {
    const int t0 = 2 * it, t1 = 2 * it + 1;
    const signed char* A0 = &LDS[(t0 & 1) << 15];
    const signed char* B0 = &LDS[65536 + ((t0 & 1) << 15)];
    const signed char* A1 = &LDS[(t1 & 1) << 15];
    const signed char* B1 = &LDS[65536 + ((t1 & 1) << 15)];

    // ---- phase 1: Q(0,kc0) of tile t0; stage A(t1)->buf1 ----
    LDB(B0, 0); LDA(A0, 0, 0);
    if (it > 0) STAGE_A(t1);
    __builtin_amdgcn_s_barrier();
    MFMA16(0);
    __builtin_amdgcn_s_barrier();

    // ---- phase 2: Q(1,kc0); stage B(t1)->buf1 ----
    LDA(A0, 1, 0);
    if (it > 0) STAGE_B(t1);
    __builtin_amdgcn_s_barrier();
    MFMA16(1);
    __builtin_amdgcn_s_barrier();

    // ---- phase 3: Q(0,kc1) ----
    LDB(B0, 64); LDA(A0, 0, 64);
    __builtin_amdgcn_s_barrier();
    MFMA16(0);
    __builtin_amdgcn_s_barrier();

    // ---- phase 4: Q(1,kc1); checkpoint: tile t1 data must be resident ----
    LDA(A0, 1, 64);
    __builtin_amdgcn_s_barrier();
    MFMA16(1);
    asm volatile("s_waitcnt vmcnt(0)" ::: "memory");  // t1 loads >=2 ph old
    __builtin_amdgcn_s_barrier();

    // ---- phase 5: Q(0,kc0) of tile t1; stage A(t0+2)->buf0 ----
    LDB(B1, 0); LDA(A1, 0, 0);
    if (it + 1 < NI) STAGE_A(t0 + 2);
    __builtin_amdgcn_s_barrier();
    MFMA16(0);
    __builtin_amdgcn_s_barrier();

    // ---- phase 6: Q(1,kc0); stage B(t0+2)->buf0 ----
    LDA(A1, 1, 0);
    if (it + 1 < NI) STAGE_B(t0 + 2);
    __builtin_amdgcn_s_barrier();
    MFMA16(1);
    __builtin_amdgcn_s_barrier();

    // ---- phase 7: Q(0,kc1) ----
    LDB(B1, 64); LDA(A1, 0, 64);
    __builtin_amdgcn_s_barrier();
    MFMA16(0);
    __builtin_amdgcn_s_barrier();

    // ---- phase 8: Q(1,kc1); checkpoint: tile t0+2 resident for next iter --
    LDA(A1, 1, 64);
    __builtin_amdgcn_s_barrier();
    MFMA16(1);
    asm volatile("s_waitcnt vmcnt(0)" ::: "memory");  // t0+2 loads >=2 ph old
    __builtin_amdgcn_s_barrier();
  }

  // ---- epilogue: C/D layout col=lane&15, row=(lane>>4)*4+reg ----
  const double wsd = *wsB;
  const int rq = (lane >> 4) << 2;
  float bv[4];
#pragma unroll
  for (int nj = 0; nj < 4; ++nj)
    bv[nj] = bias[colBase + wn * 64 + nj * 16 + rl];
#pragma unroll
  for (int mi = 0; mi < 8; ++mi) {
#pragma unroll
    for (int r = 0; r < 4; ++r) {
      const long row = rowBase + wm * 128 + mi * 16 + rq + r;
      const float sc = (float)((double)dA[row] * wsd);
      GT* crow = C + row * (long)Ncol + colBase + wn * 64 + rl;
#pragma unroll
      for (int nj = 0; nj < 4; ++nj)
        store_gt(&crow[nj * 16], (float)acc[mi][nj][r] * sc + bv[nj]);
    }
  }
}

// ---------------------------------------------------------------------------
extern "C" void kernel_launch(void* const* d_in, const int* in_sizes, int n_in,
                              void* d_out, int out_size, void* d_ws,
                              size_t ws_size, hipStream_t stream) {
  const float* x  = (const float*)d_in[0];
  const float* W1 = (const float*)d_in[1];
  const float* b1 = (const float*)d_in[2];
  const float* W2 = (const float*)d_in[3];
  const float* b2 = (const float*)d_in[4];
  const int D = in_sizes[4];             // 1024
  const int H = in_sizes[2];             // 4096
  const long M = (long)in_sizes[0] / D;  // 32768
  float* out = (float*)d_out;

  if (D != 1024 || H != 4096 || (M % 256) != 0) return;  // shape contract

  char* wsp = (char*)d_ws;
  size_t off = 0;
  auto alloc = [&](size_t bytes) {
    void* p = wsp + off;
    off = (off + bytes + 255) & ~(size_t)255;
    return p;
  };
  signed char* wq1 = (signed char*)alloc((size_t)H * D);
  signed char* wq2 = (signed char*)alloc((size_t)D * H);
  signed char* xq  = (signed char*)alloc((size_t)M * D);
  signed char* gq  = (signed char*)alloc((size_t)M * H);
  float* dx = (float*)alloc((size_t)M * 4);
  float* dg = (float*)alloc((size_t)M * 4);
  double* part = (double*)alloc(512 * 8);
  double* ws1 = (double*)alloc(8);
  double* ws2 = (double*)alloc(8);
  __hip_bfloat16* h = (__hip_bfloat16*)alloc((size_t)M * H * 2);
  if (off > ws_size) return;  // cannot run

  const long nW = (long)H * D;
  absmean_partial<<<nW / 8192, 256, 0, stream>>>(W1, part);
  absmean_final<<<1, 256, 0, stream>>>(part, ws1, (double)nW);
  absmean_partial<<<nW / 8192, 256, 0, stream>>>(W2, part);
  absmean_final<<<1, 256, 0, stream>>>(part, ws2, (double)nW);
  quant_w<<<nW / 1024, 256, 0, stream>>>(W1, ws1, wq1);
  quant_w<<<nW / 1024, 256, 0, stream>>>(W2, ws2, wq2);
  quant_rows<1024, false, float><<<M, 256, 0, stream>>>(x, xq, dx);

  const int g1 = (H / 256) * (int)(M / 256);  // 2048
  const int g2 = (D / 256) * (int)(M / 256);  // 512
  gemm_i8_m201<__hip_bfloat16><<<g1, 512, 0, stream>>>(
      xq, wq1, dx, ws1, b1, h, D, H, H / 256);
  quant_rows<4096, true, __hip_bfloat16><<<M, 256, 0, stream>>>(h, gq, dg);
  gemm_i8_m201<float><<<g2, 512, 0, stream>>>(
      gq, wq2, dg, ws2, b2, out, H, D, D / 256);
}